// Round 9
// baseline (306.843 us; speedup 1.0000x reference)
//
#include <hip/hip_runtime.h>
#include <stdint.h>

#define D_MODEL 2048
#define N_HEAD 32
#define N_KV_HEAD 8
#define HEAD_DIM 64
#define BATCH 2
#define SEQ 2048
#define ROWS (BATCH*SEQ)   // 4096
#define QKV_N 3072         // fused projection width: Q 0..2047 | K 2048..2559 | V 2560..3071

typedef __attribute__((ext_vector_type(4))) float f32x4;
typedef __attribute__((ext_vector_type(16))) float f32x16;
typedef __attribute__((ext_vector_type(8))) short bf16x8;

__device__ __forceinline__ float bflo(unsigned u){ return __uint_as_float(u << 16); }
__device__ __forceinline__ float bfhi(unsigned u){ return __uint_as_float(u & 0xFFFF0000u); }
__device__ __forceinline__ unsigned f2bf(float f){
  unsigned u = __float_as_uint(f);
  u += 0x7FFFu + ((u >> 16) & 1u);
  return u >> 16;   // RNE bf16 in low 16 bits
}
// packed f32x2 -> bf16x2 (RNE), single HW instr on gfx950
__device__ __forceinline__ unsigned cvtpk(float a, float b){
  unsigned r;
  asm("v_cvt_pk_bf16_f32 %0, %1, %2" : "=v"(r) : "v"(a), "v"(b));
  return r;
}

__device__ __forceinline__ f32x16 mfma32(bf16x8 a, bf16x8 b, f32x16 c){
  return __builtin_amdgcn_mfma_f32_32x32x16_bf16(a, b, c, 0, 0, 0);
}

__device__ __forceinline__ void async_copy16(const void* g, void* lds){
  __builtin_amdgcn_global_load_lds(
      (const __attribute__((address_space(1))) void*)g,
      (__attribute__((address_space(3))) void*)lds, 16, 0, 0);
}

// Build PV B-operand fragment (k = 8*hi + j) from 8 post-exp2 f32 values held as
// C-layout rows (reg&3)+8*(reg>>2)+4*hi. 4 cvt_pk + 2 permlane32_swap. (T12/m214)
// NOTE: inputs to the two swap operands are DISTINCT values (no register-alias hazard).
#define MKFRAG(SV, RB, OUT) {                                   \
  unsigned a0_ = cvtpk(SV[RB+0], SV[RB+1]);                     \
  unsigned b0_ = cvtpk(SV[RB+4], SV[RB+5]);                     \
  unsigned a1_ = cvtpk(SV[RB+2], SV[RB+3]);                     \
  unsigned b1_ = cvtpk(SV[RB+6], SV[RB+7]);                     \
  asm("v_permlane32_swap_b32 %0, %1" : "+v"(a0_), "+v"(b0_));   \
  asm("v_permlane32_swap_b32 %0, %1" : "+v"(a1_), "+v"(b1_));   \
  union { unsigned u[4]; bf16x8 h; } c_;                        \
  c_.u[0]=a0_; c_.u[1]=a1_; c_.u[2]=b0_; c_.u[3]=b1_;           \
  OUT = c_.h; }

// ---------------- fp32 -> bf16 elementwise ----------------
__global__ __launch_bounds__(256) void k_cvt_bf16(const float* __restrict__ in,
                                                  unsigned short* __restrict__ out, int n4){
  int i = blockIdx.x*256 + threadIdx.x;
  if (i >= n4) return;
  float4 v = ((const float4*)in)[i];
  unsigned lo = f2bf(v.x) | (f2bf(v.y) << 16);
  unsigned hi = f2bf(v.z) | (f2bf(v.w) << 16);
  ((uint2*)out)[i] = make_uint2(lo, hi);
}

// ---------------- W[K][N] fp32 -> Wt[N][K] bf16 (64x64 LDS tiles) ----------------
__global__ __launch_bounds__(256) void k_transpose_bf16(const float* __restrict__ W,
                                                        unsigned short* __restrict__ Wt,
                                                        int K, int N){
  __shared__ float tile[64][65];
  const int ntn = N >> 6;
  const int tk = blockIdx.x / ntn, tn = blockIdx.x % ntn;
  const int tid = threadIdx.x;
  #pragma unroll
  for (int i = 0; i < 4; ++i) {
    int idx4 = tid + 256*i;          // 0..1023 float4s
    int r = idx4 >> 4;
    int c4 = idx4 & 15;
    float4 v = *(const float4*)(W + (size_t)(tk*64 + r)*N + tn*64 + c4*4);
    tile[r][c4*4+0] = v.x; tile[r][c4*4+1] = v.y;
    tile[r][c4*4+2] = v.z; tile[r][c4*4+3] = v.w;
  }
  __syncthreads();
  #pragma unroll
  for (int i = 0; i < 8; ++i) {
    int o2 = tid + 256*i;            // 0..2047 bf16 pairs
    int n  = o2 >> 5;
    int k2 = o2 & 31;
    unsigned lo = f2bf(tile[k2*2+0][n]);
    unsigned hi = f2bf(tile[k2*2+1][n]);
    *(unsigned*)(Wt + (size_t)(tn*64 + n)*K + tk*64 + k2*2) = lo | (hi << 16);
  }
}

// ---------------- RoPE tables: [SEQ][32] cos & sin ----------------
__global__ __launch_bounds__(256) void k_rope_tables(float* __restrict__ ct, float* __restrict__ st){
  int gid = blockIdx.x*256 + threadIdx.x;   // SEQ*32
  int t = gid >> 5, d = gid & 31;
  float inv = exp2f(-13.287712379549449f * ((float)d * (1.0f/32.0f)));  // 10000^(-d/32)
  float a = (float)t * inv;
  ct[gid] = cosf(a);
  st[gid] = sinf(a);
}

// ---------------- RoPE in-place; thread = (row, head); optional output scale ----------------
__global__ __launch_bounds__(256) void k_rope_apply(unsigned short* __restrict__ X,
                                                    const float* __restrict__ ct,
                                                    const float* __restrict__ st,
                                                    int nheads, int stride, float scale){
  int gid = blockIdx.x*256 + threadIdx.x;
  int row = gid / nheads;
  int h = gid - row*nheads;
  int t = row & (SEQ-1);
  unsigned* p = (unsigned*)(X + (size_t)row*stride + h*HEAD_DIM);
  float o1[32], o2[32];
  #pragma unroll
  for (int d = 0; d < 32; ++d) {
    unsigned u = p[d];
    float x1 = bflo(u), x2 = bfhi(u);
    float c = ct[t*32+d], s = st[t*32+d];
    o1[d] = (x1*c - x2*s)*scale;
    o2[d] = (x1*s + x2*c)*scale;
  }
  #pragma unroll
  for (int i = 0; i < 16; ++i) {
    p[i]    = f2bf(o1[2*i]) | (f2bf(o1[2*i+1]) << 16);
    p[16+i] = f2bf(o2[2*i]) | (f2bf(o2[2*i+1]) << 16);
  }
}

// ---------------- bf16 GEMM: C[M][N] = A[M][K] * Bt[N][K]^T ----------------
template<typename OUT_T>
__global__ __launch_bounds__(256) void k_gemm_bt(const unsigned short* __restrict__ A,
                                                 const unsigned short* __restrict__ Bt,
                                                 OUT_T* __restrict__ C,
                                                 int M, int N, int K){
  __shared__ unsigned short As[128*32];
  __shared__ unsigned short Bs[128*32];
  const int nbn = N >> 7;
  const int bm = blockIdx.x / nbn, bn = blockIdx.x % nbn;
  const int m0 = bm << 7, n0 = bn << 7;
  const int tid = threadIdx.x;
  const int wid = tid >> 6, lane = tid & 63;
  const int wr = wid >> 1, wc = wid & 1;

  f32x4 acc[4][4] = {};

  const int ldr = lane >> 2;
  const int ldc = (lane & 3) * 8;
  const int fr  = lane & 15;
  const int fk  = (lane >> 4) * 8;

  for (int k0 = 0; k0 < K; k0 += 32) {
    #pragma unroll
    for (int i = 0; i < 2; ++i) {
      int chunk = wid*2 + i;
      int row = chunk*16 + ldr;
      async_copy16(A  + (size_t)(m0+row)*K + k0 + ldc, (void*)(As + chunk*512));
      async_copy16(Bt + (size_t)(n0+row)*K + k0 + ldc, (void*)(Bs + chunk*512));
    }
    __syncthreads();
    bf16x8 a[4], b[4];
    #pragma unroll
    for (int m = 0; m < 4; ++m) a[m] = *(const bf16x8*)(As + (wr*64 + m*16 + fr)*32 + fk);
    #pragma unroll
    for (int n = 0; n < 4; ++n) b[n] = *(const bf16x8*)(Bs + (wc*64 + n*16 + fr)*32 + fk);
    #pragma unroll
    for (int m = 0; m < 4; ++m)
      #pragma unroll
      for (int n = 0; n < 4; ++n)
        acc[m][n] = __builtin_amdgcn_mfma_f32_16x16x32_bf16(a[m], b[n], acc[m][n], 0, 0, 0);
    __syncthreads();
  }

  const int crow = (lane >> 4) * 4, ccol = lane & 15;
  #pragma unroll
  for (int m = 0; m < 4; ++m){
    #pragma unroll
    for (int n = 0; n < 4; ++n){
      size_t base = (size_t)(m0 + wr*64 + m*16 + crow)*N + (n0 + wc*64 + n*16 + ccol);
      #pragma unroll
      for (int j = 0; j < 4; ++j){
        float v = acc[m][n][j];
        if constexpr (sizeof(OUT_T) == 2)
          ((unsigned short*)C)[base + (size_t)j*N] = (unsigned short)f2bf(v);
        else
          ((float*)C)[base + (size_t)j*N] = v;
      }
    }
  }
}

// ---------------- V transpose: Vsrc[b*SEQ+s][kvh*64+d] (stride) -> Vt[(b*8+kvh)*64+d][s] ----------------
__global__ __launch_bounds__(256) void k_transpose_v(const unsigned short* __restrict__ Vsrc,
                                                     unsigned short* __restrict__ Vt, int stride){
  __shared__ __align__(16) unsigned short t[64*64];
  const int bk = blockIdx.x >> 5;    // b*8+kvh
  const int st = blockIdx.x & 31;    // s-tile
  const int b = bk >> 3, kvh = bk & 7;
  const int tid = threadIdx.x;
  #pragma unroll
  for (int it = 0; it < 2; ++it) {
    int i = tid + 256*it;            // 0..511 16B chunks
    int s = i >> 3, c = i & 7;
    uint4 v = *(const uint4*)(Vsrc + (size_t)(b*SEQ + st*64 + s)*stride + kvh*HEAD_DIM + c*8);
    *(uint4*)(t + s*64 + ((c ^ (s&7))*8)) = v;   // chunk-swizzled store
  }
  __syncthreads();
  const int d = tid & 63;
  const int w = tid >> 6;
  #pragma unroll
  for (int it = 0; it < 2; ++it) {
    int seg = w + it*4;              // s-chunk of 8
    unsigned short tmp[8];
    #pragma unroll
    for (int k = 0; k < 8; ++k) {
      int s = seg*8 + k;
      tmp[k] = t[s*64 + (((d>>3) ^ (s&7))*8) + (d&7)];
    }
    *(uint4*)(Vt + ((size_t)bk*64 + d)*SEQ + st*64 + seg*8) = *(uint4*)tmp;
  }
}

// ---------------- MFMA flash attention: unpaired all-resident, quad-balanced ----------------
// 1024 blocks, one (b,h,128-row q-tile) item each -> 4 blocks/CU all co-resident
// (16 waves/CU). rank->item mapping: consecutive quads of 4 ranks share one bh (same KV
// stream -> L1/L2 locality) with qt in {15-c, c, 8+c, 7-c} (uniform 68-tile load per quad),
// XCD swizzle on top. Per item: wave = 32 q rows. Swapped QK^T via mfma_32x32x16 (A=K,B=Q);
// softmax in-register, log2 domain (Q pre-scaled), defer-max; P -> PV B-operand via
// cvt_pk + permlane32_swap; cross-half reductions via __shfl_xor(.,32).
// Pipeline: full K+V double buffer (2x16KB); ONE barrier per tile:
//   { vmcnt(0); barrier; issue stage(t+1) into buf^1; compute from buf }.
__global__ __launch_bounds__(256) void k_attn_mfma(const unsigned short* __restrict__ Q,
                                                   const unsigned short* __restrict__ Kb,
                                                   const unsigned short* __restrict__ Vt,
                                                   unsigned short* __restrict__ O,
                                                   const int* __restrict__ maskp){
  __shared__ __align__(16) char smem[32768];   // buf0: K 8K | V 8K ; buf1: K 8K | V 8K
  const int orig = blockIdx.x;
  const int rank = (orig & 7)*128 + (orig >> 3);   // XCD swizzle (1024, bijective)
  const int j  = rank & 3;
  const int i  = rank >> 2;
  const int bh = i & 63;
  const int c  = (i >> 6) & 3;
  const int b = bh >> 5, h = bh & 31;
  const int kvh = h >> 2;
  // quad-balanced qt: {15-c, c, 8+c, 7-c} -> per-quad tile load uniform (68)
  const int qt = (j == 0) ? (15 - c) : (j == 1) ? c : (j == 2) ? (8 + c) : (7 - c);

  const int tid = threadIdx.x;
  const int wid = tid >> 6, lane = tid & 63;
  const int ql = lane & 31, hi = lane >> 5;
  const int sw = lane & 7;              // LDS chunk swizzle key
  const bool causal = (maskp[0] != 0);

  const int q0 = qt*128;
  const int qg = q0 + 32*wid + ql;      // this lane's global q row
  const int nt = causal ? (2*qt + 2) : (SEQ/64);

  // Q fragments (B-operand): lane holds Q[q=ql][d = 16dd + 8hi + j]
  const unsigned short* qbase = Q + (size_t)(b*SEQ + qg)*QKV_N + h*HEAD_DIM + 8*hi;
  bf16x8 qf[4];
  #pragma unroll
  for (int dd = 0; dd < 4; ++dd) qf[dd] = *(const bf16x8*)(qbase + 16*dd);

  f32x16 acc[2] = {};       // O^T: acc[dt] -> d = (r&3)+8*(r>>2)+4hi+32dt, q = ql
  float mrun = -1e30f, lrun = 0.f;

  // stage K+V tile into buf (pre-swizzled global source, linear LDS dest)
  auto stage = [&](int tile, int bufbase){
    const int s0s = tile*64;
    #pragma unroll
    for (int it = 0; it < 2; ++it) {
      int ii = (wid*2+it)*64 + lane;    // 16B chunk index 0..511
      int s = ii >> 3, cc = ii & 7;     // row, chunk-in-row
      async_copy16(Kb + (size_t)(b*SEQ + s0s + s)*QKV_N + kvh*HEAD_DIM + ((cc ^ (s&7))*8),
                   smem + bufbase + (wid*2+it)*1024);
      async_copy16(Vt + ((size_t)(b*N_KV_HEAD + kvh)*HEAD_DIM + s)*SEQ + s0s + ((cc ^ (s&7))*8),
                   smem + bufbase + 8192 + (wid*2+it)*1024);
    }
  };

  stage(0, 0);

  for (int t = 0; t < nt; ++t) {
    const int s0 = t*64;
    const int cur = t & 1;

    asm volatile("s_waitcnt vmcnt(0)" ::: "memory");   // stage(t) landed
    __syncthreads();                                   // visible to all; prior reads done
    if (t+1 < nt) stage(t+1, (cur^1)*16384);           // overlaps compute(t)

    const char* Kbuf = smem + cur*16384;
    const char* Vbuf = Kbuf + 8192;

    // wave-uniform: skip fully-masked tiles (waves 0-1 at the upper diagonal tile)
    const bool skipw = causal && (s0 > q0 + 32*wid + 31);
    if (skipw) continue;                               // barrier at next iter top syncs

    // QK^T swapped: sa0/sa1 rows s = s0 + 32st + (r&3)+8*(r>>2)+4hi, col q = ql
    f32x16 sa0 = {}, sa1 = {};
    __builtin_amdgcn_s_setprio(1);
    #pragma unroll
    for (int dd = 0; dd < 4; ++dd) {
      int co = ((2*dd + hi) ^ sw) * 16;
      bf16x8 k0 = *(const bf16x8*)(Kbuf + ql*128 + co);
      bf16x8 k1 = *(const bf16x8*)(Kbuf + (ql+32)*128 + co);
      sa0 = mfma32(k0, qf[dd], sa0);
      sa1 = mfma32(k1, qf[dd], sa1);
    }
    __builtin_amdgcn_s_setprio(0);

    // causal mask, only where the tile crosses this wave's diagonal
    const bool domask = causal && (s0 + 63 > q0 + 32*wid);
    if (domask) {
      #pragma unroll
      for (int r = 0; r < 16; ++r) {
        int sl = (r&3) + 8*(r>>2) + 4*hi;
        if (s0 + sl > qg)      sa0[r] = -3.0e38f;
        if (s0 + 32 + sl > qg) sa1[r] = -3.0e38f;
      }
    }

    // in-lane max tree + cross-half shfl reduce
    float c4[4] = {-3.0e38f, -3.0e38f, -3.0e38f, -3.0e38f};
    #pragma unroll
    for (int r = 0; r < 16; ++r)
      c4[r&3] = fmaxf(c4[r&3], fmaxf(sa0[r], sa1[r]));
    float cmax = fmaxf(fmaxf(c4[0], c4[1]), fmaxf(c4[2], c4[3]));
    cmax = fmaxf(cmax, __shfl_xor(cmax, 32));

    if (!__all(cmax <= mrun + 8.0f)) {   // defer-max (T13), log2 domain
      float mnew = fmaxf(mrun, cmax);
      float r2 = exp2f(mrun - mnew);
      lrun *= r2;
      #pragma unroll
      for (int r = 0; r < 16; ++r) { acc[0][r] *= r2; acc[1][r] *= r2; }
      mrun = mnew;
    }
    float s4[4] = {0.f, 0.f, 0.f, 0.f};
    #pragma unroll
    for (int r = 0; r < 16; ++r) {
      float e0 = exp2f(sa0[r] - mrun);
      float e1 = exp2f(sa1[r] - mrun);
      sa0[r] = e0; sa1[r] = e1;
      s4[r&3] += e0 + e1;
    }
    float tsum = (s4[0] + s4[1]) + (s4[2] + s4[3]);
    tsum += __shfl_xor(tsum, 32);
    lrun += tsum;

    // P -> PV B-operand fragments, fully in-register
    bf16x8 pf0, pf1, pf2, pf3;        // ssub 0..3 (s 0-15,16-31,32-47,48-63)
    MKFRAG(sa0, 0, pf0); MKFRAG(sa0, 8, pf1);
    MKFRAG(sa1, 0, pf2); MKFRAG(sa1, 8, pf3);

    // PV: O^T += V^T * P^T
    __builtin_amdgcn_s_setprio(1);
    #pragma unroll
    for (int dt = 0; dt < 2; ++dt) {
      const char* vb = Vbuf + (ql + 32*dt)*128;
      bf16x8 v0 = *(const bf16x8*)(vb + (((0+hi) ^ sw)*16));
      bf16x8 v1 = *(const bf16x8*)(vb + (((2+hi) ^ sw)*16));
      bf16x8 v2 = *(const bf16x8*)(vb + (((4+hi) ^ sw)*16));
      bf16x8 v3 = *(const bf16x8*)(vb + (((6+hi) ^ sw)*16));
      acc[dt] = mfma32(v0, pf0, acc[dt]);
      acc[dt] = mfma32(v1, pf1, acc[dt]);
      acc[dt] = mfma32(v2, pf2, acc[dt]);
      acc[dt] = mfma32(v3, pf3, acc[dt]);
    }
    __builtin_amdgcn_s_setprio(0);
  }

  // epilogue: O^T -> LDS [q][d] (bf16, swizzled; reuse buffers) -> coalesced store
  __syncthreads();                     // all waves done with K/V buffers
  float inv = 1.0f / lrun;
  char* osm = smem + wid*4096;         // per-wave 32 rows x 128B
  #pragma unroll
  for (int dt = 0; dt < 2; ++dt) {
    #pragma unroll
    for (int r = 0; r < 16; r += 2) {
      unsigned w = cvtpk(acc[dt][r]*inv, acc[dt][r+1]*inv);
      int chunk = (r>>2) + 4*dt;
      int byteo = ql*128 + ((chunk ^ (ql&7))*16) + 8*hi + ((r&2)<<1);
      *(unsigned*)(osm + byteo) = w;
    }
  }
  __syncthreads();
  #pragma unroll
  for (int it = 0; it < 4; ++it) {
    int idx = tid + 256*it;            // 0..1023: 128 rows x 8 chunks
    int row = idx >> 3, ch = idx & 7;
    uint4 v = *(const uint4*)(smem + (row>>5)*4096 + (row&31)*128 + ((ch ^ (row&7))*16));
    *(uint4*)(O + (size_t)(b*SEQ + q0 + row)*D_MODEL + h*HEAD_DIM + ch*8) = v;
  }
}

extern "C" void kernel_launch(void* const* d_in, const int* in_sizes, int n_in,
                              void* d_out, int out_size, void* d_ws, size_t ws_size,
                              hipStream_t stream){
  const float* x  = (const float*)d_in[0];
  const float* Wq = (const float*)d_in[1];
  const float* Wk = (const float*)d_in[2];
  const float* Wv = (const float*)d_in[3];
  const float* Wo = (const float*)d_in[4];
  const int* maskp = (const int*)d_in[5];
  float* out = (float*)d_out;

  char* ws = (char*)d_ws;
  unsigned short* xb    = (unsigned short*)(ws);               // 16 MB [4096][2048]
  unsigned short* AO    = (unsigned short*)(ws);               // 16 MB (xb dead after QKV GEMM)
  unsigned short* Wqkvt = (unsigned short*)(ws + 16777216);    // 12 MB [3072][2048]
  unsigned short* Vt    = (unsigned short*)(ws + 16777216);    //  4 MB (Wqkvt dead after QKV GEMM)
  unsigned short* Wot   = (unsigned short*)(ws + 29360128);    //  8 MB [2048][2048]
  unsigned short* QKVb  = (unsigned short*)(ws + 37748736);    // 24 MB [4096][3072]
  float* ct = (float*)(ws + 62914560);                         // 256 KB [2048][32]
  float* st = (float*)(ws + 63176704);                         // 256 KB

  k_cvt_bf16<<<8192, 256, 0, stream>>>(x, xb, ROWS*D_MODEL/4);
  k_transpose_bf16<<<1024, 256, 0, stream>>>(Wq, Wqkvt,                          D_MODEL, 2048);
  k_transpose_bf16<<<256,  256, 0, stream>>>(Wk, Wqkvt + (size_t)2048*D_MODEL,   D_MODEL, 512);
  k_transpose_bf16<<<256,  256, 0, stream>>>(Wv, Wqkvt + (size_t)2560*D_MODEL,   D_MODEL, 512);
  k_transpose_bf16<<<1024, 256, 0, stream>>>(Wo, Wot, D_MODEL, 2048);
  k_rope_tables<<<SEQ*32/256, 256, 0, stream>>>(ct, st);

  // fused QKV projection: [4096][3072]
  k_gemm_bt<unsigned short><<<(4096/128)*(QKV_N/128), 256, 0, stream>>>(xb, Wqkvt, QKVb, 4096, QKV_N, 2048);

  // Q pre-scaled by 0.125*log2(e) so QK^T lands in log2 domain
  k_rope_apply<<<ROWS*N_HEAD/256,    256, 0, stream>>>(QKVb,        ct, st, N_HEAD,    QKV_N, 0.18033688011112042f);
  k_rope_apply<<<ROWS*N_KV_HEAD/256, 256, 0, stream>>>(QKVb + 2048, ct, st, N_KV_HEAD, QKV_N, 1.0f);

  k_transpose_v<<<BATCH*N_KV_HEAD*(SEQ/64), 256, 0, stream>>>(QKVb + 2560, Vt, QKV_N);

  // unpaired all-resident grid: 1024 items, quad-balanced static mapping
  k_attn_mfma<<<1024, 256, 0, stream>>>(QKVb, QKVb + 2048, Vt, AO, maskp);

  k_gemm_bt<float><<<(4096/128)*(2048/128), 256, 0, stream>>>(AO, Wot, out, 4096, 2048, 2048);
}

// Round 10
// 247.483 us; speedup vs baseline: 1.2399x; 1.2399x over previous
//
#include <hip/hip_runtime.h>
#include <stdint.h>

#define D_MODEL 2048
#define N_HEAD 32
#define N_KV_HEAD 8
#define HEAD_DIM 64
#define BATCH 2
#define SEQ 2048
#define ROWS (BATCH*SEQ)   // 4096
#define QKV_N 3072         // fused projection width: Q 0..2047 | K 2048..2559 | V 2560..3071
#define SCL2F 0.18033688011112042f   // 0.125 * log2(e)

typedef __attribute__((ext_vector_type(4))) float f32x4;
typedef __attribute__((ext_vector_type(8))) short bf16x8;

__device__ __forceinline__ float bflo(unsigned u){ return __uint_as_float(u << 16); }
__device__ __forceinline__ float bfhi(unsigned u){ return __uint_as_float(u & 0xFFFF0000u); }
__device__ __forceinline__ unsigned f2bf(float f){
  unsigned u = __float_as_uint(f);
  u += 0x7FFFu + ((u >> 16) & 1u);
  return u >> 16;   // RNE bf16 in low 16 bits
}
// packed f32x2 -> bf16x2 (RNE), single HW instr on gfx950
__device__ __forceinline__ unsigned cvtpk(float a, float b){
  unsigned r;
  asm("v_cvt_pk_bf16_f32 %0, %1, %2" : "=v"(r) : "v"(a), "v"(b));
  return r;
}

__device__ __forceinline__ void async_copy16(const void* g, void* lds){
  __builtin_amdgcn_global_load_lds(
      (const __attribute__((address_space(1))) void*)g,
      (__attribute__((address_space(3))) void*)lds, 16, 0, 0);
}

// ---------------- fp32 -> bf16 elementwise ----------------
__global__ __launch_bounds__(256) void k_cvt_bf16(const float* __restrict__ in,
                                                  unsigned short* __restrict__ out, int n4){
  int i = blockIdx.x*256 + threadIdx.x;
  if (i >= n4) return;
  float4 v = ((const float4*)in)[i];
  unsigned lo = f2bf(v.x) | (f2bf(v.y) << 16);
  unsigned hi = f2bf(v.z) | (f2bf(v.w) << 16);
  ((uint2*)out)[i] = make_uint2(lo, hi);
}

// ---------------- all 4 weight transposes in ONE launch ----------------
// W[K=2048][N] fp32 -> Wt[N][2048] bf16, 64x64 LDS tiles.
// blocks 0..1023: Wq->Wqkvt rows 0..2047 | 1024..1279: Wk->rows 2048..2559 |
// 1280..1535: Wv->rows 2560..3071 | 1536..2559: Wo->Wot.
__global__ __launch_bounds__(256) void k_transpose_all(const float* __restrict__ Wq,
                                                       const float* __restrict__ Wk,
                                                       const float* __restrict__ Wv,
                                                       const float* __restrict__ Wo,
                                                       unsigned short* __restrict__ Wqkvt,
                                                       unsigned short* __restrict__ Wot){
  const int bid = blockIdx.x;
  const float* W; unsigned short* Wt; int N; int rel;
  if (bid < 1024)      { W = Wq; Wt = Wqkvt;                         N = 2048; rel = bid; }
  else if (bid < 1280) { W = Wk; Wt = Wqkvt + (size_t)2048*D_MODEL;  N = 512;  rel = bid - 1024; }
  else if (bid < 1536) { W = Wv; Wt = Wqkvt + (size_t)2560*D_MODEL;  N = 512;  rel = bid - 1280; }
  else                 { W = Wo; Wt = Wot;                           N = 2048; rel = bid - 1536; }
  __shared__ float tile[64][65];
  const int ntn = N >> 6;
  const int tk = rel / ntn, tn = rel % ntn;
  const int tid = threadIdx.x;
  #pragma unroll
  for (int i = 0; i < 4; ++i) {
    int idx4 = tid + 256*i;          // 0..1023 float4s
    int r = idx4 >> 4;
    int c4 = idx4 & 15;
    float4 v = *(const float4*)(W + (size_t)(tk*64 + r)*N + tn*64 + c4*4);
    tile[r][c4*4+0] = v.x; tile[r][c4*4+1] = v.y;
    tile[r][c4*4+2] = v.z; tile[r][c4*4+3] = v.w;
  }
  __syncthreads();
  #pragma unroll
  for (int i = 0; i < 8; ++i) {
    int o2 = tid + 256*i;            // 0..2047 bf16 pairs
    int n  = o2 >> 5;
    int k2 = o2 & 31;
    unsigned lo = f2bf(tile[k2*2+0][n]);
    unsigned hi = f2bf(tile[k2*2+1][n]);
    *(unsigned*)(Wt + (size_t)(tn*64 + n)*D_MODEL + tk*64 + k2*2) = lo | (hi << 16);
  }
}

// ---------------- RoPE tables: [SEQ][32] cos & sin ----------------
__global__ __launch_bounds__(256) void k_rope_tables(float* __restrict__ ct, float* __restrict__ st){
  int gid = blockIdx.x*256 + threadIdx.x;   // SEQ*32
  int t = gid >> 5, d = gid & 31;
  float inv = exp2f(-13.287712379549449f * ((float)d * (1.0f/32.0f)));  // 10000^(-d/32)
  float a = (float)t * inv;
  ct[gid] = cosf(a);
  st[gid] = sinf(a);
}

// ---------------- RoPE in-place (K only); thread = (row, head) ----------------
__global__ __launch_bounds__(256) void k_rope_apply(unsigned short* __restrict__ X,
                                                    const float* __restrict__ ct,
                                                    const float* __restrict__ st,
                                                    int nheads, int stride, float scale){
  int gid = blockIdx.x*256 + threadIdx.x;
  int row = gid / nheads;
  int h = gid - row*nheads;
  int t = row & (SEQ-1);
  unsigned* p = (unsigned*)(X + (size_t)row*stride + h*HEAD_DIM);
  float o1[32], o2[32];
  #pragma unroll
  for (int d = 0; d < 32; ++d) {
    unsigned u = p[d];
    float x1 = bflo(u), x2 = bfhi(u);
    float c = ct[t*32+d], s = st[t*32+d];
    o1[d] = (x1*c - x2*s)*scale;
    o2[d] = (x1*s + x2*c)*scale;
  }
  #pragma unroll
  for (int i = 0; i < 16; ++i) {
    p[i]    = f2bf(o1[2*i]) | (f2bf(o1[2*i+1]) << 16);
    p[16+i] = f2bf(o2[2*i]) | (f2bf(o2[2*i+1]) << 16);
  }
}

// ---------------- bf16 GEMM: C[M][N] = A[M][K] * Bt[N][K]^T ----------------
template<typename OUT_T>
__global__ __launch_bounds__(256) void k_gemm_bt(const unsigned short* __restrict__ A,
                                                 const unsigned short* __restrict__ Bt,
                                                 OUT_T* __restrict__ C,
                                                 int M, int N, int K){
  __shared__ unsigned short As[128*32];
  __shared__ unsigned short Bs[128*32];
  const int nbn = N >> 7;
  const int bm = blockIdx.x / nbn, bn = blockIdx.x % nbn;
  const int m0 = bm << 7, n0 = bn << 7;
  const int tid = threadIdx.x;
  const int wid = tid >> 6, lane = tid & 63;
  const int wr = wid >> 1, wc = wid & 1;

  f32x4 acc[4][4] = {};

  const int ldr = lane >> 2;
  const int ldc = (lane & 3) * 8;
  const int fr  = lane & 15;
  const int fk  = (lane >> 4) * 8;

  for (int k0 = 0; k0 < K; k0 += 32) {
    #pragma unroll
    for (int i = 0; i < 2; ++i) {
      int chunk = wid*2 + i;
      int row = chunk*16 + ldr;
      async_copy16(A  + (size_t)(m0+row)*K + k0 + ldc, (void*)(As + chunk*512));
      async_copy16(Bt + (size_t)(n0+row)*K + k0 + ldc, (void*)(Bs + chunk*512));
    }
    __syncthreads();
    bf16x8 a[4], b[4];
    #pragma unroll
    for (int m = 0; m < 4; ++m) a[m] = *(const bf16x8*)(As + (wr*64 + m*16 + fr)*32 + fk);
    #pragma unroll
    for (int n = 0; n < 4; ++n) b[n] = *(const bf16x8*)(Bs + (wc*64 + n*16 + fr)*32 + fk);
    #pragma unroll
    for (int m = 0; m < 4; ++m)
      #pragma unroll
      for (int n = 0; n < 4; ++n)
        acc[m][n] = __builtin_amdgcn_mfma_f32_16x16x32_bf16(a[m], b[n], acc[m][n], 0, 0, 0);
    __syncthreads();
  }

  const int crow = (lane >> 4) * 4, ccol = lane & 15;
  #pragma unroll
  for (int m = 0; m < 4; ++m){
    #pragma unroll
    for (int n = 0; n < 4; ++n){
      size_t base = (size_t)(m0 + wr*64 + m*16 + crow)*N + (n0 + wc*64 + n*16 + ccol);
      #pragma unroll
      for (int j = 0; j < 4; ++j){
        float v = acc[m][n][j];
        if constexpr (sizeof(OUT_T) == 2)
          ((unsigned short*)C)[base + (size_t)j*N] = (unsigned short)f2bf(v);
        else
          ((float*)C)[base + (size_t)j*N] = v;
      }
    }
  }
}

// ---------------- V transpose: Vsrc[b*SEQ+s][kvh*64+d] (stride) -> Vt[(b*8+kvh)*64+d][s] ----------------
__global__ __launch_bounds__(256) void k_transpose_v(const unsigned short* __restrict__ Vsrc,
                                                     unsigned short* __restrict__ Vt, int stride){
  __shared__ __align__(16) unsigned short t[64*64];
  const int bk = blockIdx.x >> 5;    // b*8+kvh
  const int st = blockIdx.x & 31;    // s-tile
  const int b = bk >> 3, kvh = bk & 7;
  const int tid = threadIdx.x;
  #pragma unroll
  for (int it = 0; it < 2; ++it) {
    int i = tid + 256*it;            // 0..511 16B chunks
    int s = i >> 3, c = i & 7;
    uint4 v = *(const uint4*)(Vsrc + (size_t)(b*SEQ + st*64 + s)*stride + kvh*HEAD_DIM + c*8);
    *(uint4*)(t + s*64 + ((c ^ (s&7))*8)) = v;   // chunk-swizzled store
  }
  __syncthreads();
  const int d = tid & 63;
  const int w = tid >> 6;
  #pragma unroll
  for (int it = 0; it < 2; ++it) {
    int seg = w + it*4;              // s-chunk of 8
    unsigned short tmp[8];
    #pragma unroll
    for (int k = 0; k < 8; ++k) {
      int s = seg*8 + k;
      tmp[k] = t[s*64 + (((d>>3) ^ (s&7))*8) + (d&7)];
    }
    *(uint4*)(Vt + ((size_t)bk*64 + d)*SEQ + st*64 + seg*8) = *(uint4*)tmp;
  }
}

// ---------------- MFMA flash attention (R5-proven structure + fused Q-RoPE) ----------------
// block = 256 thr (4 waves); block = (b, h, q-tile PAIR {31-j, j}) -> uniform 33 tiles/block.
// Per pass: wave = 16 q rows. Q is read RAW; RoPE + 0.125*log2(e) scale applied in-register
// (cvtpk RNE -> bit-identical to the old memory round-trip). Scores emerge in log2 domain.
// Swapped QK^T (S^T = K*Q^T) -> in-register log2 softmax (defer-max, cvt_pk pack) ->
// P via wave-private LDS -> O^T = mfma(A=V^T, B=P^T).
// LDS: K double-buffered (2x8K), V single-buffered (8K; staged after post-PV barrier,
// drained at next iter's vmcnt(0) under QK+softmax), P 4x2K. Total 32KB.
__global__ __launch_bounds__(256) void k_attn_mfma(const unsigned short* __restrict__ Q,
                                                   const unsigned short* __restrict__ Kb,
                                                   const unsigned short* __restrict__ Vt,
                                                   unsigned short* __restrict__ O,
                                                   const int* __restrict__ maskp,
                                                   const float* __restrict__ ct,
                                                   const float* __restrict__ st){
  __shared__ __align__(16) char smem[32768];   // K0 8K | K1 8K | V 8K | P 4x2K
  char* Vsm = smem + 16384;
  const int orig = blockIdx.x;
  const int bid = (orig & 7)*128 + (orig >> 3);   // XCD swizzle (1024 blocks, bijective)
  const int jj = bid & 15;
  const int h  = (bid >> 4) & 31;
  const int b  = bid >> 9;
  const int kvh = h >> 2;
  const int tid = threadIdx.x;
  const int wid = tid >> 6, lane = tid & 63;
  const int q_ = lane & 15, g = lane >> 4;
  char* Psm = smem + 24576 + wid*2048;
  const bool causal = (maskp[0] != 0);

  auto stageK = [&](int tile, int bufbase){
    const int s0s = tile*64;
    #pragma unroll
    for (int it = 0; it < 2; ++it) {
      int i = (wid*2+it)*64 + lane;     // 16B chunk index 0..511
      int s = i >> 3, c = i & 7;        // row, chunk-in-row
      async_copy16(Kb + (size_t)(b*SEQ + s0s + s)*QKV_N + kvh*HEAD_DIM + ((c ^ (s&7))*8),
                   smem + bufbase + (wid*2+it)*1024);
    }
  };
  auto stageV = [&](int tile){
    const int s0s = tile*64;
    #pragma unroll
    for (int it = 0; it < 2; ++it) {
      int i = (wid*2+it)*64 + lane;
      int s = i >> 3, c = i & 7;        // s = d-row of Vt tile
      async_copy16(Vt + ((size_t)(b*N_KV_HEAD + kvh)*HEAD_DIM + s)*SEQ + s0s + ((c ^ (s&7))*8),
                   Vsm + (wid*2+it)*1024);
    }
  };

  for (int pass = 0; pass < 2; ++pass) {
    const int qt = pass ? jj : (31 - jj);   // long pass first
    const int q0 = qt*64;
    const int qg = q0 + 16*wid + q_;
    const int nt = causal ? (qt+1) : (SEQ/64);

    // fused Q-RoPE: lane needs post-rope Q[qg][d], d = 8g..8g+7 (qf0) and 32+8g.. (qf1).
    // Both derive from raw in[16g..16g+15] and cos/sin[j], j = 8g..8g+7.
    bf16x8 qf0, qf1;
    {
      const int trow = qg;              // position in sequence (qg < SEQ)
      const unsigned short* qsrc = Q + (size_t)(b*SEQ + trow)*QKV_N + h*HEAD_DIM + g*16;
      union { bf16x8 h; unsigned u[4]; } xa, xb;
      xa.h = *(const bf16x8*)(qsrc);
      xb.h = *(const bf16x8*)(qsrc + 8);
      const float4* cp = (const float4*)(ct + trow*32 + g*8);
      const float4* sp = (const float4*)(st + trow*32 + g*8);
      float4 c0 = cp[0], c1 = cp[1];
      float4 s0 = sp[0], s1 = sp[1];
      float cc[8] = {c0.x,c0.y,c0.z,c0.w,c1.x,c1.y,c1.z,c1.w};
      float ss[8] = {s0.x,s0.y,s0.z,s0.w,s1.x,s1.y,s1.z,s1.w};
      float e0[8], e1[8];
      #pragma unroll
      for (int e = 0; e < 8; ++e) {
        unsigned u = (e < 4) ? xa.u[e] : xb.u[e-4];
        float x1 = bflo(u), x2 = bfhi(u);
        float cs = cc[e]*SCL2F, sn = ss[e]*SCL2F;
        e0[e] = x1*cs - x2*sn;          // d = 8g+e  (< 32)
        e1[e] = x1*sn + x2*cs;          // d = 32+8g+e
      }
      union { unsigned u[4]; bf16x8 h; } p0, p1;
      #pragma unroll
      for (int m = 0; m < 4; ++m) {
        p0.u[m] = cvtpk(e0[2*m], e0[2*m+1]);
        p1.u[m] = cvtpk(e1[2*m], e1[2*m+1]);
      }
      qf0 = p0.h; qf1 = p1.h;
    }

    f32x4 acc[4] = {};        // O^T: acc[m] -> d=16m+4g+r, q=lane&15
    float mrun = -1e30f, lrun = 0.f;

    stageK(0, 0);
    stageV(0);
    asm volatile("s_waitcnt vmcnt(0)" ::: "memory");
    __syncthreads();

    for (int t = 0; t < nt; ++t) {
      const int s0 = t*64;
      const int cur = t & 1;
      const char* Kbuf = smem + cur*8192;

      if (t+1 < nt) stageK(t+1, (cur^1)*8192);

      // QK^T swapped: sa[f] holds S[q=lane&15][s=s0+16f+4g+r], already log2-scaled
      f32x4 sa[4];
      __builtin_amdgcn_s_setprio(1);
      #pragma unroll
      for (int f = 0; f < 4; ++f) {
        const char* kb = Kbuf + (16*f + q_)*128;
        bf16x8 a0 = *(const bf16x8*)(kb + ((g ^ (q_&7))*16));
        bf16x8 a1 = *(const bf16x8*)(kb + (((g+4) ^ (q_&7))*16));
        f32x4 z = {};
        z = __builtin_amdgcn_mfma_f32_16x16x32_bf16(a0, qf0, z, 0, 0, 0);
        z = __builtin_amdgcn_mfma_f32_16x16x32_bf16(a1, qf1, z, 0, 0, 0);
        sa[f] = z;
      }
      __builtin_amdgcn_s_setprio(0);

      // log2-domain softmax with defer-max (T13)
      const bool domask = causal && (t == qt);
      float x[4][4];
      float cm[4];
      #pragma unroll
      for (int f = 0; f < 4; ++f) {
        #pragma unroll
        for (int r = 0; r < 4; ++r) {
          float v = sa[f][r];
          if (domask && (s0 + 16*f + 4*g + r > qg)) v = -3.0e38f;
          x[f][r] = v;
        }
        cm[f] = fmaxf(fmaxf(x[f][0], x[f][1]), fmaxf(x[f][2], x[f][3]));
      }
      float cmax = fmaxf(fmaxf(cm[0], cm[1]), fmaxf(cm[2], cm[3]));
      cmax = fmaxf(cmax, __shfl_xor(cmax, 16));
      cmax = fmaxf(cmax, __shfl_xor(cmax, 32));
      if (!__all(cmax <= mrun + 8.0f)) {
        float mnew = fmaxf(mrun, cmax);
        float r2 = exp2f(mrun - mnew);
        lrun *= r2;
        #pragma unroll
        for (int m = 0; m < 4; ++m) {
          acc[m][0] *= r2; acc[m][1] *= r2; acc[m][2] *= r2; acc[m][3] *= r2;
        }
        mrun = mnew;
      }
      // exp2 + tree-sum + cvt_pk pack + ds_write_b64 per f
      float sf[4];
      #pragma unroll
      for (int f = 0; f < 4; ++f) {
        float e0 = exp2f(x[f][0] - mrun);
        float e1 = exp2f(x[f][1] - mrun);
        float e2 = exp2f(x[f][2] - mrun);
        float e3 = exp2f(x[f][3] - mrun);
        sf[f] = (e0 + e1) + (e2 + e3);
        uint2 w = { cvtpk(e0, e1), cvtpk(e2, e3) };
        int byteo = q_*128 + (((2*f + (g>>1)) ^ (q_&7))*16) + (g&1)*8;
        *(uint2*)(Psm + byteo) = w;
      }
      float tsum = (sf[0] + sf[1]) + (sf[2] + sf[3]);
      tsum += __shfl_xor(tsum, 16);
      tsum += __shfl_xor(tsum, 32);
      lrun += tsum;

      // drain own K(t+1) + own V(t); barrier -> K(t+1)/V(t) valid everywhere
      asm volatile("s_waitcnt vmcnt(0)" ::: "memory");
      __syncthreads();

      // PV: O^T += V^T * P^T
      __builtin_amdgcn_s_setprio(1);
      #pragma unroll
      for (int kh = 0; kh < 2; ++kh) {
        bf16x8 pb = *(const bf16x8*)(Psm + q_*128 + (((g + 4*kh) ^ (q_&7))*16));
        #pragma unroll
        for (int m = 0; m < 4; ++m) {
          bf16x8 va = *(const bf16x8*)(Vsm + (16*m + q_)*128 + (((g + 4*kh) ^ (q_&7))*16));
          acc[m] = __builtin_amdgcn_mfma_f32_16x16x32_bf16(va, pb, acc[m], 0, 0, 0);
        }
      }
      __builtin_amdgcn_s_setprio(0);

      __syncthreads();                 // all Vbuf readers done -> safe to restage
      if (t+1 < nt) stageV(t+1);       // drains at next iter's vmcnt(0), under QK+softmax
    }

    // epilogue: O^T -> LDS (bf16, swizzled) -> row-major coalesced global store
    float inv = 1.0f / lrun;
    #pragma unroll
    for (int m = 0; m < 4; ++m) {
      uint2 w = { cvtpk(acc[m][0]*inv, acc[m][1]*inv), cvtpk(acc[m][2]*inv, acc[m][3]*inv) };
      int byteo = q_*128 + (((2*m + (g>>1)) ^ (q_&7))*16) + (g&1)*8;
      *(uint2*)(Psm + byteo) = w;
    }
    #pragma unroll
    for (int cc = 0; cc < 2; ++cc) {
      int row = lane >> 2;               // q-local
      int ch = (lane & 3)*2 + cc;        // d-chunk
      uint4 v = *(const uint4*)(Psm + row*128 + ((ch ^ (row&7))*16));
      *(uint4*)(O + (size_t)(b*SEQ + q0 + 16*wid + row)*D_MODEL + h*HEAD_DIM + ch*8) = v;
    }
  }
}

extern "C" void kernel_launch(void* const* d_in, const int* in_sizes, int n_in,
                              void* d_out, int out_size, void* d_ws, size_t ws_size,
                              hipStream_t stream){
  const float* x  = (const float*)d_in[0];
  const float* Wq = (const float*)d_in[1];
  const float* Wk = (const float*)d_in[2];
  const float* Wv = (const float*)d_in[3];
  const float* Wo = (const float*)d_in[4];
  const int* maskp = (const int*)d_in[5];
  float* out = (float*)d_out;

  char* ws = (char*)d_ws;
  unsigned short* xb    = (unsigned short*)(ws);               // 16 MB [4096][2048]
  unsigned short* AO    = (unsigned short*)(ws);               // 16 MB (xb dead after QKV GEMM)
  unsigned short* Wqkvt = (unsigned short*)(ws + 16777216);    // 12 MB [3072][2048]
  unsigned short* Vt    = (unsigned short*)(ws + 16777216);    //  4 MB (Wqkvt dead after QKV GEMM)
  unsigned short* Wot   = (unsigned short*)(ws + 29360128);    //  8 MB [2048][2048]
  unsigned short* QKVb  = (unsigned short*)(ws + 37748736);    // 24 MB [4096][3072]
  float* ct = (float*)(ws + 62914560);                         // 256 KB [2048][32]
  float* st = (float*)(ws + 63176704);                         // 256 KB

  k_cvt_bf16<<<8192, 256, 0, stream>>>(x, xb, ROWS*D_MODEL/4);
  k_transpose_all<<<2560, 256, 0, stream>>>(Wq, Wk, Wv, Wo, Wqkvt, Wot);
  k_rope_tables<<<SEQ*32/256, 256, 0, stream>>>(ct, st);

  // fused QKV projection: [4096][3072]
  k_gemm_bt<unsigned short><<<(4096/128)*(QKV_N/128), 256, 0, stream>>>(xb, Wqkvt, QKVb, 4096, QKV_N, 2048);

  // RoPE in memory only for K (Q-rope is fused into the attention kernel)
  k_rope_apply<<<ROWS*N_KV_HEAD/256, 256, 0, stream>>>(QKVb + 2048, ct, st, N_KV_HEAD, QKV_N, 1.0f);

  k_transpose_v<<<BATCH*N_KV_HEAD*(SEQ/64), 256, 0, stream>>>(QKVb + 2560, Vt, QKV_N);

  // causal-pair-balanced grid: (b, h, pair j) -> 2*32*16 = 1024 uniform blocks
  k_attn_mfma<<<BATCH*N_HEAD*16, 256, 0, stream>>>(QKVb, QKVb + 2048, Vt, AO, maskp, ct, st);

  k_gemm_bt<float><<<(4096/128)*(2048/128), 256, 0, stream>>>(AO, Wot, out, 4096, 2048, 2048);
}

// Round 11
// 240.499 us; speedup vs baseline: 1.2759x; 1.0290x over previous
//
#include <hip/hip_runtime.h>
#include <stdint.h>

#define D_MODEL 2048
#define N_HEAD 32
#define N_KV_HEAD 8
#define HEAD_DIM 64
#define BATCH 2
#define SEQ 2048
#define ROWS (BATCH*SEQ)   // 4096
#define QKV_N 3072         // fused projection width: Q 0..2047 | K 2048..2559 | V 2560..3071
#define SCL2F 0.18033688011112042f   // 0.125 * log2(e)

typedef __attribute__((ext_vector_type(4))) float f32x4;
typedef __attribute__((ext_vector_type(8))) short bf16x8;

__device__ __forceinline__ float bflo(unsigned u){ return __uint_as_float(u << 16); }
__device__ __forceinline__ float bfhi(unsigned u){ return __uint_as_float(u & 0xFFFF0000u); }
__device__ __forceinline__ unsigned f2bf(float f){
  unsigned u = __float_as_uint(f);
  u += 0x7FFFu + ((u >> 16) & 1u);
  return u >> 16;   // RNE bf16 in low 16 bits
}
// packed f32x2 -> bf16x2 (RNE), single HW instr on gfx950
__device__ __forceinline__ unsigned cvtpk(float a, float b){
  unsigned r;
  asm("v_cvt_pk_bf16_f32 %0, %1, %2" : "=v"(r) : "v"(a), "v"(b));
  return r;
}

__device__ __forceinline__ void async_copy16(const void* g, void* lds){
  __builtin_amdgcn_global_load_lds(
      (const __attribute__((address_space(1))) void*)g,
      (__attribute__((address_space(3))) void*)lds, 16, 0, 0);
}

// ---------------- fused prep: fp32->bf16 cvt | 4 weight transposes | RoPE tables ----------------
// blocks 0..8191: x -> xb (bf16). 8192..10751: weight transposes (64x64 tiles).
// 10752..11007: rope cos/sin tables.
__global__ __launch_bounds__(256) void k_prep(const float* __restrict__ x,
                                              const float* __restrict__ Wq,
                                              const float* __restrict__ Wk,
                                              const float* __restrict__ Wv,
                                              const float* __restrict__ Wo,
                                              unsigned short* __restrict__ xb,
                                              unsigned short* __restrict__ Wqkvt,
                                              unsigned short* __restrict__ Wot,
                                              float* __restrict__ ct,
                                              float* __restrict__ st){
  __shared__ float tile[64][65];
  const int bid = blockIdx.x;
  const int tid = threadIdx.x;
  if (bid < 8192) {
    int i = bid*256 + tid;           // ROWS*D_MODEL/4 = 2097152 float4s
    float4 v = ((const float4*)x)[i];
    unsigned lo = f2bf(v.x) | (f2bf(v.y) << 16);
    unsigned hi = f2bf(v.z) | (f2bf(v.w) << 16);
    ((uint2*)xb)[i] = make_uint2(lo, hi);
    return;
  }
  if (bid < 10752) {
    const int rel0 = bid - 8192;     // 0..2559
    const float* W; unsigned short* Wt; int N; int rel;
    if (rel0 < 1024)      { W = Wq; Wt = Wqkvt;                         N = 2048; rel = rel0; }
    else if (rel0 < 1280) { W = Wk; Wt = Wqkvt + (size_t)2048*D_MODEL;  N = 512;  rel = rel0 - 1024; }
    else if (rel0 < 1536) { W = Wv; Wt = Wqkvt + (size_t)2560*D_MODEL;  N = 512;  rel = rel0 - 1280; }
    else                  { W = Wo; Wt = Wot;                           N = 2048; rel = rel0 - 1536; }
    const int ntn = N >> 6;
    const int tk = rel / ntn, tn = rel % ntn;
    #pragma unroll
    for (int i = 0; i < 4; ++i) {
      int idx4 = tid + 256*i;        // 0..1023 float4s
      int r = idx4 >> 4;
      int c4 = idx4 & 15;
      float4 v = *(const float4*)(W + (size_t)(tk*64 + r)*N + tn*64 + c4*4);
      tile[r][c4*4+0] = v.x; tile[r][c4*4+1] = v.y;
      tile[r][c4*4+2] = v.z; tile[r][c4*4+3] = v.w;
    }
    __syncthreads();
    #pragma unroll
    for (int i = 0; i < 8; ++i) {
      int o2 = tid + 256*i;          // 0..2047 bf16 pairs
      int n  = o2 >> 5;
      int k2 = o2 & 31;
      unsigned lo = f2bf(tile[k2*2+0][n]);
      unsigned hi = f2bf(tile[k2*2+1][n]);
      *(unsigned*)(Wt + (size_t)(tn*64 + n)*D_MODEL + tk*64 + k2*2) = lo | (hi << 16);
    }
    return;
  }
  {
    int gid = (bid - 10752)*256 + tid;   // SEQ*32
    int t = gid >> 5, d = gid & 31;
    float inv = exp2f(-13.287712379549449f * ((float)d * (1.0f/32.0f)));  // 10000^(-d/32)
    float a = (float)t * inv;
    ct[gid] = cosf(a);
    st[gid] = sinf(a);
  }
}

// ---------------- RoPE in-place (K only); thread = (row, head) ----------------
__global__ __launch_bounds__(256) void k_rope_apply(unsigned short* __restrict__ X,
                                                    const float* __restrict__ ct,
                                                    const float* __restrict__ st,
                                                    int nheads, int stride, float scale){
  int gid = blockIdx.x*256 + threadIdx.x;
  int row = gid / nheads;
  int h = gid - row*nheads;
  int t = row & (SEQ-1);
  unsigned* p = (unsigned*)(X + (size_t)row*stride + h*HEAD_DIM);
  float o1[32], o2[32];
  #pragma unroll
  for (int d = 0; d < 32; ++d) {
    unsigned u = p[d];
    float x1 = bflo(u), x2 = bfhi(u);
    float c = ct[t*32+d], s = st[t*32+d];
    o1[d] = (x1*c - x2*s)*scale;
    o2[d] = (x1*s + x2*c)*scale;
  }
  #pragma unroll
  for (int i = 0; i < 16; ++i) {
    p[i]    = f2bf(o1[2*i]) | (f2bf(o1[2*i+1]) << 16);
    p[16+i] = f2bf(o2[2*i]) | (f2bf(o2[2*i+1]) << 16);
  }
}

// ---------------- bf16 GEMM: C[M][N] = A[M][K] * Bt[N][K]^T  (+ XCD swizzle, T1) ----------------
template<typename OUT_T>
__global__ __launch_bounds__(256) void k_gemm_bt(const unsigned short* __restrict__ A,
                                                 const unsigned short* __restrict__ Bt,
                                                 OUT_T* __restrict__ C,
                                                 int M, int N, int K){
  __shared__ unsigned short As[128*32];
  __shared__ unsigned short Bs[128*32];
  const int nbn = N >> 7;
  // XCD swizzle (grid % 8 == 0 for both call sites -> bijective)
  const int bswz = ((int)blockIdx.x & 7)*((int)gridDim.x >> 3) + ((int)blockIdx.x >> 3);
  const int bm = bswz / nbn, bn = bswz % nbn;
  const int m0 = bm << 7, n0 = bn << 7;
  const int tid = threadIdx.x;
  const int wid = tid >> 6, lane = tid & 63;
  const int wr = wid >> 1, wc = wid & 1;

  f32x4 acc[4][4] = {};

  const int ldr = lane >> 2;
  const int ldc = (lane & 3) * 8;
  const int fr  = lane & 15;
  const int fk  = (lane >> 4) * 8;

  for (int k0 = 0; k0 < K; k0 += 32) {
    #pragma unroll
    for (int i = 0; i < 2; ++i) {
      int chunk = wid*2 + i;
      int row = chunk*16 + ldr;
      async_copy16(A  + (size_t)(m0+row)*K + k0 + ldc, (void*)(As + chunk*512));
      async_copy16(Bt + (size_t)(n0+row)*K + k0 + ldc, (void*)(Bs + chunk*512));
    }
    __syncthreads();
    bf16x8 a[4], b[4];
    #pragma unroll
    for (int m = 0; m < 4; ++m) a[m] = *(const bf16x8*)(As + (wr*64 + m*16 + fr)*32 + fk);
    #pragma unroll
    for (int n = 0; n < 4; ++n) b[n] = *(const bf16x8*)(Bs + (wc*64 + n*16 + fr)*32 + fk);
    #pragma unroll
    for (int m = 0; m < 4; ++m)
      #pragma unroll
      for (int n = 0; n < 4; ++n)
        acc[m][n] = __builtin_amdgcn_mfma_f32_16x16x32_bf16(a[m], b[n], acc[m][n], 0, 0, 0);
    __syncthreads();
  }

  const int crow = (lane >> 4) * 4, ccol = lane & 15;
  #pragma unroll
  for (int m = 0; m < 4; ++m){
    #pragma unroll
    for (int n = 0; n < 4; ++n){
      size_t base = (size_t)(m0 + wr*64 + m*16 + crow)*N + (n0 + wc*64 + n*16 + ccol);
      #pragma unroll
      for (int j = 0; j < 4; ++j){
        float v = acc[m][n][j];
        if constexpr (sizeof(OUT_T) == 2)
          ((unsigned short*)C)[base + (size_t)j*N] = (unsigned short)f2bf(v);
        else
          ((float*)C)[base + (size_t)j*N] = v;
      }
    }
  }
}

// ---------------- V transpose: Vsrc[b*SEQ+s][kvh*64+d] (stride) -> Vt[(b*8+kvh)*64+d][s] ----------------
__global__ __launch_bounds__(256) void k_transpose_v(const unsigned short* __restrict__ Vsrc,
                                                     unsigned short* __restrict__ Vt, int stride){
  __shared__ __align__(16) unsigned short t[64*64];
  const int bk = blockIdx.x >> 5;    // b*8+kvh
  const int st = blockIdx.x & 31;    // s-tile
  const int b = bk >> 3, kvh = bk & 7;
  const int tid = threadIdx.x;
  #pragma unroll
  for (int it = 0; it < 2; ++it) {
    int i = tid + 256*it;            // 0..511 16B chunks
    int s = i >> 3, c = i & 7;
    uint4 v = *(const uint4*)(Vsrc + (size_t)(b*SEQ + st*64 + s)*stride + kvh*HEAD_DIM + c*8);
    *(uint4*)(t + s*64 + ((c ^ (s&7))*8)) = v;   // chunk-swizzled store
  }
  __syncthreads();
  const int d = tid & 63;
  const int w = tid >> 6;
  #pragma unroll
  for (int it = 0; it < 2; ++it) {
    int seg = w + it*4;              // s-chunk of 8
    unsigned short tmp[8];
    #pragma unroll
    for (int k = 0; k < 8; ++k) {
      int s = seg*8 + k;
      tmp[k] = t[s*64 + (((d>>3) ^ (s&7))*8) + (d&7)];
    }
    *(uint4*)(Vt + ((size_t)bk*64 + d)*SEQ + st*64 + seg*8) = *(uint4*)tmp;
  }
}

// ---------------- MFMA flash attention (R5 structure + fused Q-RoPE + ones-row l) ----------------
// block = 256 thr (4 waves); block = (b, h, q-tile PAIR {31-j, j}) -> uniform 33 tiles/block.
// Per pass: wave = 16 q rows. Q read RAW; RoPE + 0.125*log2(e) applied in-register.
// Swapped QK^T (S^T = K*Q^T) -> in-register log2 softmax (defer-max, cvt_pk pack) ->
// P via wave-private LDS -> O^T = mfma(A=V^T, B=P^T).
// Softmax DENOMINATOR via MFMA ones-trick: accl = mfma(ones, P^T, accl) follows the
// exact same rescale recurrence as acc -> removes 15 adds + 2 shfls per tile from VALU.
// LDS: K dbuf 2x8K | V 8K | P 4x2K = 32KB.
__global__ __launch_bounds__(256) void k_attn_mfma(const unsigned short* __restrict__ Q,
                                                   const unsigned short* __restrict__ Kb,
                                                   const unsigned short* __restrict__ Vt,
                                                   unsigned short* __restrict__ O,
                                                   const int* __restrict__ maskp,
                                                   const float* __restrict__ ct,
                                                   const float* __restrict__ st){
  __shared__ __align__(16) char smem[32768];   // K0 8K | K1 8K | V 8K | P 4x2K
  char* Vsm = smem + 16384;
  const int orig = blockIdx.x;
  const int bid = (orig & 7)*128 + (orig >> 3);   // XCD swizzle (1024 blocks, bijective)
  const int jj = bid & 15;
  const int h  = (bid >> 4) & 31;
  const int b  = bid >> 9;
  const int kvh = h >> 2;
  const int tid = threadIdx.x;
  const int wid = tid >> 6, lane = tid & 63;
  const int q_ = lane & 15, g = lane >> 4;
  char* Psm = smem + 24576 + wid*2048;
  const bool causal = (maskp[0] != 0);

  bf16x8 onesf;                      // A-operand of all bf16 1.0
  #pragma unroll
  for (int e = 0; e < 8; ++e) onesf[e] = (short)0x3F80;

  auto stageK = [&](int tile, int bufbase){
    const int s0s = tile*64;
    #pragma unroll
    for (int it = 0; it < 2; ++it) {
      int i = (wid*2+it)*64 + lane;     // 16B chunk index 0..511
      int s = i >> 3, c = i & 7;        // row, chunk-in-row
      async_copy16(Kb + (size_t)(b*SEQ + s0s + s)*QKV_N + kvh*HEAD_DIM + ((c ^ (s&7))*8),
                   smem + bufbase + (wid*2+it)*1024);
    }
  };
  auto stageV = [&](int tile){
    const int s0s = tile*64;
    #pragma unroll
    for (int it = 0; it < 2; ++it) {
      int i = (wid*2+it)*64 + lane;
      int s = i >> 3, c = i & 7;        // s = d-row of Vt tile
      async_copy16(Vt + ((size_t)(b*N_KV_HEAD + kvh)*HEAD_DIM + s)*SEQ + s0s + ((c ^ (s&7))*8),
                   Vsm + (wid*2+it)*1024);
    }
  };

  for (int pass = 0; pass < 2; ++pass) {
    const int qt = pass ? jj : (31 - jj);   // long pass first
    const int q0 = qt*64;
    const int qg = q0 + 16*wid + q_;
    const int nt = causal ? (qt+1) : (SEQ/64);

    // fused Q-RoPE: lane needs post-rope Q[qg][d], d = 8g..8g+7 (qf0) and 32+8g.. (qf1).
    bf16x8 qf0, qf1;
    {
      const int trow = qg;
      const unsigned short* qsrc = Q + (size_t)(b*SEQ + trow)*QKV_N + h*HEAD_DIM + g*16;
      union { bf16x8 h; unsigned u[4]; } xa, xb;
      xa.h = *(const bf16x8*)(qsrc);
      xb.h = *(const bf16x8*)(qsrc + 8);
      const float4* cp = (const float4*)(ct + trow*32 + g*8);
      const float4* sp = (const float4*)(st + trow*32 + g*8);
      float4 c0 = cp[0], c1 = cp[1];
      float4 s0 = sp[0], s1 = sp[1];
      float cc[8] = {c0.x,c0.y,c0.z,c0.w,c1.x,c1.y,c1.z,c1.w};
      float ss[8] = {s0.x,s0.y,s0.z,s0.w,s1.x,s1.y,s1.z,s1.w};
      float e0[8], e1[8];
      #pragma unroll
      for (int e = 0; e < 8; ++e) {
        unsigned u = (e < 4) ? xa.u[e] : xb.u[e-4];
        float x1 = bflo(u), x2 = bfhi(u);
        float cs = cc[e]*SCL2F, sn = ss[e]*SCL2F;
        e0[e] = x1*cs - x2*sn;          // d = 8g+e  (< 32)
        e1[e] = x1*sn + x2*cs;          // d = 32+8g+e
      }
      union { unsigned u[4]; bf16x8 h; } p0, p1;
      #pragma unroll
      for (int m = 0; m < 4; ++m) {
        p0.u[m] = cvtpk(e0[2*m], e0[2*m+1]);
        p1.u[m] = cvtpk(e1[2*m], e1[2*m+1]);
      }
      qf0 = p0.h; qf1 = p1.h;
    }

    f32x4 acc[4] = {};        // O^T: acc[m] -> d=16m+4g+r, q=lane&15
    f32x4 accl = {};          // ones-row: accl[r] = sum_s P[q][s] (same rescale as acc)
    float mrun = -1e30f;

    stageK(0, 0);
    stageV(0);
    asm volatile("s_waitcnt vmcnt(0)" ::: "memory");
    __syncthreads();

    for (int t = 0; t < nt; ++t) {
      const int s0 = t*64;
      const int cur = t & 1;
      const char* Kbuf = smem + cur*8192;

      if (t+1 < nt) stageK(t+1, (cur^1)*8192);

      // QK^T swapped: sa[f] holds S[q=lane&15][s=s0+16f+4g+r], already log2-scaled
      f32x4 sa[4];
      __builtin_amdgcn_s_setprio(1);
      #pragma unroll
      for (int f = 0; f < 4; ++f) {
        const char* kb = Kbuf + (16*f + q_)*128;
        bf16x8 a0 = *(const bf16x8*)(kb + ((g ^ (q_&7))*16));
        bf16x8 a1 = *(const bf16x8*)(kb + (((g+4) ^ (q_&7))*16));
        f32x4 z = {};
        z = __builtin_amdgcn_mfma_f32_16x16x32_bf16(a0, qf0, z, 0, 0, 0);
        z = __builtin_amdgcn_mfma_f32_16x16x32_bf16(a1, qf1, z, 0, 0, 0);
        sa[f] = z;
      }
      __builtin_amdgcn_s_setprio(0);

      // log2-domain softmax with defer-max (T13)
      const bool domask = causal && (t == qt);
      float x[4][4];
      float cm[4];
      #pragma unroll
      for (int f = 0; f < 4; ++f) {
        #pragma unroll
        for (int r = 0; r < 4; ++r) {
          float v = sa[f][r];
          if (domask && (s0 + 16*f + 4*g + r > qg)) v = -3.0e38f;
          x[f][r] = v;
        }
        cm[f] = fmaxf(fmaxf(x[f][0], x[f][1]), fmaxf(x[f][2], x[f][3]));
      }
      float cmax = fmaxf(fmaxf(cm[0], cm[1]), fmaxf(cm[2], cm[3]));
      cmax = fmaxf(cmax, __shfl_xor(cmax, 16));
      cmax = fmaxf(cmax, __shfl_xor(cmax, 32));
      if (!__all(cmax <= mrun + 8.0f)) {
        float mnew = fmaxf(mrun, cmax);
        float r2 = exp2f(mrun - mnew);
        #pragma unroll
        for (int m = 0; m < 4; ++m) {
          acc[m][0] *= r2; acc[m][1] *= r2; acc[m][2] *= r2; acc[m][3] *= r2;
        }
        accl[0] *= r2; accl[1] *= r2; accl[2] *= r2; accl[3] *= r2;
        mrun = mnew;
      }
      // exp2 + cvt_pk pack + ds_write_b64 per f (denominator handled by ones-MFMA)
      #pragma unroll
      for (int f = 0; f < 4; ++f) {
        float e0 = exp2f(x[f][0] - mrun);
        float e1 = exp2f(x[f][1] - mrun);
        float e2 = exp2f(x[f][2] - mrun);
        float e3 = exp2f(x[f][3] - mrun);
        uint2 w = { cvtpk(e0, e1), cvtpk(e2, e3) };
        int byteo = q_*128 + (((2*f + (g>>1)) ^ (q_&7))*16) + (g&1)*8;
        *(uint2*)(Psm + byteo) = w;
      }

      // drain own K(t+1) + own V(t); barrier -> K(t+1)/V(t) valid everywhere
      asm volatile("s_waitcnt vmcnt(0)" ::: "memory");
      __syncthreads();

      // PV: O^T += V^T * P^T ; ones-row accumulates the softmax denominator
      __builtin_amdgcn_s_setprio(1);
      #pragma unroll
      for (int kh = 0; kh < 2; ++kh) {
        bf16x8 pb = *(const bf16x8*)(Psm + q_*128 + (((g + 4*kh) ^ (q_&7))*16));
        accl = __builtin_amdgcn_mfma_f32_16x16x32_bf16(onesf, pb, accl, 0, 0, 0);
        #pragma unroll
        for (int m = 0; m < 4; ++m) {
          bf16x8 va = *(const bf16x8*)(Vsm + (16*m + q_)*128 + (((g + 4*kh) ^ (q_&7))*16));
          acc[m] = __builtin_amdgcn_mfma_f32_16x16x32_bf16(va, pb, acc[m], 0, 0, 0);
        }
      }
      __builtin_amdgcn_s_setprio(0);

      __syncthreads();                 // all Vbuf readers done -> safe to restage
      if (t+1 < nt) stageV(t+1);       // drains at next iter's vmcnt(0), under QK+softmax
    }

    // epilogue: O^T -> LDS (bf16, swizzled) -> row-major coalesced global store
    float inv = 1.0f / accl[0];        // all rows of ones-MFMA output are identical
    #pragma unroll
    for (int m = 0; m < 4; ++m) {
      uint2 w = { cvtpk(acc[m][0]*inv, acc[m][1]*inv), cvtpk(acc[m][2]*inv, acc[m][3]*inv) };
      int byteo = q_*128 + (((2*m + (g>>1)) ^ (q_&7))*16) + (g&1)*8;
      *(uint2*)(Psm + byteo) = w;
    }
    #pragma unroll
    for (int cc = 0; cc < 2; ++cc) {
      int row = lane >> 2;               // q-local
      int ch = (lane & 3)*2 + cc;        // d-chunk
      uint4 v = *(const uint4*)(Psm + row*128 + ((ch ^ (row&7))*16));
      *(uint4*)(O + (size_t)(b*SEQ + q0 + 16*wid + row)*D_MODEL + h*HEAD_DIM + ch*8) = v;
    }
  }
}

extern "C" void kernel_launch(void* const* d_in, const int* in_sizes, int n_in,
                              void* d_out, int out_size, void* d_ws, size_t ws_size,
                              hipStream_t stream){
  const float* x  = (const float*)d_in[0];
  const float* Wq = (const float*)d_in[1];
  const float* Wk = (const float*)d_in[2];
  const float* Wv = (const float*)d_in[3];
  const float* Wo = (const float*)d_in[4];
  const int* maskp = (const int*)d_in[5];
  float* out = (float*)d_out;

  char* ws = (char*)d_ws;
  unsigned short* xb    = (unsigned short*)(ws);               // 16 MB [4096][2048]
  unsigned short* AO    = (unsigned short*)(ws);               // 16 MB (xb dead after QKV GEMM)
  unsigned short* Wqkvt = (unsigned short*)(ws + 16777216);    // 12 MB [3072][2048]
  unsigned short* Vt    = (unsigned short*)(ws + 16777216);    //  4 MB (Wqkvt dead after QKV GEMM)
  unsigned short* Wot   = (unsigned short*)(ws + 29360128);    //  8 MB [2048][2048]
  unsigned short* QKVb  = (unsigned short*)(ws + 37748736);    // 24 MB [4096][3072]
  float* ct = (float*)(ws + 62914560);                         // 256 KB [2048][32]
  float* st = (float*)(ws + 63176704);                         // 256 KB

  // fused prep: cvt (8192) | weight transposes (2560) | rope tables (256)
  k_prep<<<11008, 256, 0, stream>>>(x, Wq, Wk, Wv, Wo, xb, Wqkvt, Wot, ct, st);

  // fused QKV projection: [4096][3072]
  k_gemm_bt<unsigned short><<<(4096/128)*(QKV_N/128), 256, 0, stream>>>(xb, Wqkvt, QKVb, 4096, QKV_N, 2048);

  // RoPE in memory only for K (Q-rope is fused into the attention kernel)
  k_rope_apply<<<ROWS*N_KV_HEAD/256, 256, 0, stream>>>(QKVb + 2048, ct, st, N_KV_HEAD, QKV_N, 1.0f);

  k_transpose_v<<<BATCH*N_KV_HEAD*(SEQ/64), 256, 0, stream>>>(QKVb + 2560, Vt, QKV_N);

  // causal-pair-balanced grid: (b, h, pair j) -> 2*32*16 = 1024 uniform blocks
  k_attn_mfma<<<BATCH*N_HEAD*16, 256, 0, stream>>>(QKVb, QKVb + 2048, Vt, AO, maskp, ct, st);

  k_gemm_bt<float><<<(4096/128)*(2048/128), 256, 0, stream>>>(AO, Wot, out, 4096, 2048, 2048);
}